// Round 9
// baseline (228.326 us; speedup 1.0000x reference)
//
#include <hip/hip_runtime.h>

typedef __bf16 bf16;
typedef bf16 bf16x8 __attribute__((ext_vector_type(8)));
typedef bf16 bf16x4 __attribute__((ext_vector_type(4)));
typedef float f32x4 __attribute__((ext_vector_type(4)));

#define B_ 4
#define T_ 4096
#define C_ 1024
#define EPS_ 1e-6f
#define KVTSTR 16448  // 16384 + 64 pad

typedef __attribute__((address_space(1))) const void* as1p;
typedef __attribute__((address_space(3))) void* as3p;

// ---------------- cast f32 -> bf16 (vectorized, 8/thread) ----------------
__global__ void cast_kernel(const float* __restrict__ in, bf16* __restrict__ out, int n8) {
  int i = blockIdx.x * blockDim.x + threadIdx.x;
  int stride = gridDim.x * blockDim.x;
  for (; i < n8; i += stride) {
    const float4* p = (const float4*)(in + (size_t)i * 8);
    float4 v0 = p[0];
    float4 v1 = p[1];
    bf16x8 o;
    o[0] = (bf16)v0.x; o[1] = (bf16)v0.y; o[2] = (bf16)v0.z; o[3] = (bf16)v0.w;
    o[4] = (bf16)v1.x; o[5] = (bf16)v1.y; o[6] = (bf16)v1.z; o[7] = (bf16)v1.w;
    *(bf16x8*)(out + (size_t)i * 8) = o;
  }
}

// ---------------- 4-phase NT GEMM: C = A[M][K] * B[N][K]^T ----------------
// BM=BN=256, BK=64, 512 thr (8 waves, 2M x 4N, wave tile 128x64), double-buffered
// 128KB LDS. Per K-tile: 4 phases {ds_read subtile; [stage 4 gloads of tile T+1];
// bar; lgkm0; 16 MFMA; bar}. ONE vmcnt(0) per tile at end of phase 3 (spill-proof:
// no counted-vmcnt invariants; stages issued phases 0-1 have ~2.5 phases of cover).
#define BM 256
#define BN 256
#define BK 64
#define KD 1024
#define NTI (KD / BK)                  // 16
#define TILB 32768                     // one operand tile: 256*64*2B
#define BUFB (2 * TILB)                // A + B = 65536
#define SMEMB (2 * BUFB)               // 131072

#define STG(p, ko, dst) __builtin_amdgcn_global_load_lds((as1p)((p) + (ko)), (as3p)(dst), 16, 0, 0)

// load A-frags for M-rows MI0, MI0+1 of this wave
#define LDA(MI0)                                                                       \
  _Pragma("unroll") for (int a = 0; a < 2; a++)                                        \
    _Pragma("unroll") for (int kk = 0; kk < 2; kk++)                                   \
      af[a][kk] = *(const bf16x8*)(Ab + (wm * 128 + ((MI0) + a) * 16 + fr) * 64 + swz[kk]);

// 16 MFMAs for M-rows MI0, MI0+1
#define MM(MI0)                                                                        \
  __builtin_amdgcn_s_setprio(1);                                                       \
  _Pragma("unroll") for (int a = 0; a < 2; a++)                                        \
    _Pragma("unroll") for (int nj = 0; nj < 4; nj++)                                   \
      _Pragma("unroll") for (int kk = 0; kk < 2; kk++)                                 \
        acc[(MI0) + a][nj] = __builtin_amdgcn_mfma_f32_16x16x32_bf16(af[a][kk], bfr[nj][kk], acc[(MI0) + a][nj], 0, 0, 0); \
  __builtin_amdgcn_s_setprio(0);

#define BAR1 { __builtin_amdgcn_s_barrier(); asm volatile("s_waitcnt lgkmcnt(0)" ::: "memory"); __builtin_amdgcn_sched_barrier(0); }
#define BAR2 { __builtin_amdgcn_s_barrier(); __builtin_amdgcn_sched_barrier(0); }

template <int MODE>
__global__ __launch_bounds__(512, 1) void gemm9(
    const bf16* __restrict__ A, const bf16* __restrict__ Bm,
    void* __restrict__ Cout, const float* __restrict__ bias,
    bf16* __restrict__ kvt, int M, int N, int tiles_n) {
  extern __shared__ char smem[];
  const int tid = threadIdx.x;
  const int l = tid & 63;
  const int w = tid >> 6;
  const int wm = w >> 2;   // 0..1  (M: 2 x 128)
  const int wn = w & 3;    // 0..3  (N: 4 x 64)

  const int cpx = gridDim.x >> 3;
  const int bid = (blockIdx.x & 7) * cpx + (blockIdx.x >> 3);
  const int tm = (bid / tiles_n) * BM;
  const int tn = (bid % tiles_n) * BN;

  // staging: thread covers row tid>>3 of a 64-row group, chunk tid&7 (16B);
  // LDS dest linear (tid*16); source chunk = (tid&7) ^ (row&7) (rule #21: inverse
  // swizzle on the global source, same XOR applied on the read side).
  const int gsw = ((tid & 7) ^ ((tid >> 3) & 7)) * 8;
  const int tsr = tid >> 3;

  const bf16* pA0 = A + (size_t)(tm + tsr) * KD + gsw;
  const bf16* pA1 = A + (size_t)(tm + 64 + tsr) * KD + gsw;
  const bf16* pA2 = A + (size_t)(tm + 128 + tsr) * KD + gsw;
  const bf16* pA3 = A + (size_t)(tm + 192 + tsr) * KD + gsw;
  const bf16* pB0 = Bm + (size_t)(tn + tsr) * KD + gsw;
  const bf16* pB1 = Bm + (size_t)(tn + 64 + tsr) * KD + gsw;
  const bf16* pB2 = Bm + (size_t)(tn + 128 + tsr) * KD + gsw;
  const bf16* pB3 = Bm + (size_t)(tn + 192 + tsr) * KD + gsw;

  // fragment read: row = base + fr (row&7 == fr&7); logical chunk c = kk*4+fc,
  // physical = c ^ (row&7)
  const int fr = l & 15;
  const int fc = l >> 4;
  int swz[2];
  swz[0] = ((0 * 4 + fc) ^ (fr & 7)) * 8;
  swz[1] = ((1 * 4 + fc) ^ (fr & 7)) * 8;

  f32x4 acc[8][4] = {};

  // prologue: stage tile 0 into buf0, full drain (robust)
  STG(pA0, 0, smem + tid * 16);
  STG(pA1, 0, smem + 8192 + tid * 16);
  STG(pA2, 0, smem + 16384 + tid * 16);
  STG(pA3, 0, smem + 24576 + tid * 16);
  STG(pB0, 0, smem + TILB + tid * 16);
  STG(pB1, 0, smem + TILB + 8192 + tid * 16);
  STG(pB2, 0, smem + TILB + 16384 + tid * 16);
  STG(pB3, 0, smem + TILB + 24576 + tid * 16);
  asm volatile("s_waitcnt vmcnt(0)" ::: "memory");
  __builtin_amdgcn_s_barrier();
  __builtin_amdgcn_sched_barrier(0);

  for (int t = 0; t < NTI; ++t) {
    const bf16* Ab = (const bf16*)(smem + (t & 1) * BUFB);
    const bf16* Bb = (const bf16*)(smem + (t & 1) * BUFB + TILB);
    char* sd = smem + ((t & 1) ^ 1) * BUFB;
    const bool st = (t + 1 < NTI);
    const int ko = (t + 1) * BK;
    bf16x8 bfr[4][2], af[2][2];

    // ---- phase 0: all B frags + A mi0,1; stage B of tile t+1 ----
#pragma unroll
    for (int nj = 0; nj < 4; nj++)
#pragma unroll
      for (int kk = 0; kk < 2; kk++)
        bfr[nj][kk] = *(const bf16x8*)(Bb + (wn * 64 + nj * 16 + fr) * 64 + swz[kk]);
    LDA(0)
    if (st) {
      STG(pB0, ko, sd + TILB + tid * 16);
      STG(pB1, ko, sd + TILB + 8192 + tid * 16);
      STG(pB2, ko, sd + TILB + 16384 + tid * 16);
      STG(pB3, ko, sd + TILB + 24576 + tid * 16);
    }
    BAR1 MM(0) BAR2

    // ---- phase 1: A mi2,3; stage A of tile t+1 ----
    LDA(2)
    if (st) {
      STG(pA0, ko, sd + tid * 16);
      STG(pA1, ko, sd + 8192 + tid * 16);
      STG(pA2, ko, sd + 16384 + tid * 16);
      STG(pA3, ko, sd + 24576 + tid * 16);
    }
    BAR1 MM(2) BAR2

    // ---- phase 2: A mi4,5 ----
    LDA(4)
    BAR1 MM(4) BAR2

    // ---- phase 3: A mi6,7; end-of-tile full drain ----
    LDA(6)
    BAR1 MM(6)
    asm volatile("s_waitcnt vmcnt(0)" ::: "memory");
    BAR2
  }

  // ---------------- epilogue: C/D col = lane&15, row = (lane>>4)*4 + r ----------------
  const int crow0 = tm + wm * 128 + (l >> 4) * 4;
  const int ccol0 = tn + wn * 64 + (l & 15);
  if (MODE == 0) {
    if (tn < 1024) {
      bf16* qbuf = (bf16*)Cout;
#pragma unroll
      for (int mi = 0; mi < 8; mi++)
#pragma unroll
        for (int nj = 0; nj < 4; nj++) {
          const int col = ccol0 + nj * 16;
#pragma unroll
          for (int r = 0; r < 4; r++) {
            const int row = crow0 + mi * 16 + r;
            float v = acc[mi][nj][r];
            v = (v > 0.f) ? (v + 1.0f) : __expf(v);
            qbuf[(size_t)row * 1024 + col] = (bf16)v;
          }
        }
    } else {
#pragma unroll
      for (int mi = 0; mi < 8; mi++)
#pragma unroll
        for (int nj = 0; nj < 4; nj++) {
          const int colp = ccol0 + nj * 16 - 1024;
          const bool isk = (colp < 1024);
          bf16x4 pk;
#pragma unroll
          for (int r = 0; r < 4; r++) {
            float v = acc[mi][nj][r];
            if (isk) v = (v > 0.f) ? (v + 1.0f) : __expf(v);
            pk[r] = (bf16)v;
          }
          const int n0 = crow0 + mi * 16;
          *(bf16x4*)(kvt + (size_t)colp * KVTSTR + n0) = pk;
        }
    }
  } else {
    float* Cf = (float*)Cout;
#pragma unroll
    for (int mi = 0; mi < 8; mi++)
#pragma unroll
      for (int nj = 0; nj < 4; nj++) {
        const int col = ccol0 + nj * 16;
        const float bv = bias[col];
#pragma unroll
        for (int r = 0; r < 4; r++) {
          const int row = crow0 + mi * 16 + r;
          Cf[(size_t)row * N + col] = acc[mi][nj][r] + bv;
        }
      }
  }
}

// ---------------- kvgemm: partial kv[d][m] (+ksum) per (kchunk, b, h) via MFMA ----------
__global__ __launch_bounds__(256) void kvgemm(const bf16* __restrict__ kvt,
                                              float* __restrict__ partial) {
  const int kc = blockIdx.x >> 6;
  const int bh = blockIdx.x & 63;
  const int b = bh >> 4, h = bh & 15;
  const int l = threadIdx.x & 63;
  const int w = threadIdx.x >> 6;

  const size_t nb = (size_t)b * 4096 + kc * 1024 + (l >> 4) * 8;
  const bf16* Ar = kvt + (size_t)(h * 64 + w * 16 + (l & 15)) * KVTSTR + nb;
  const bf16* Br = kvt + (size_t)(1024 + h * 64 + (l & 15)) * KVTSTR + nb;

  f32x4 acc[4] = {};
  float ks = 0.f;
  bf16x8 aC, bC[4], aN, bN[4];
  aC = *(const bf16x8*)Ar;
#pragma unroll
  for (int nj = 0; nj < 4; nj++) bC[nj] = *(const bf16x8*)(Br + (size_t)nj * 16 * KVTSTR);

  for (int it = 0; it < 32; ++it) {
    if (it + 1 < 32) {
      aN = *(const bf16x8*)(Ar + (it + 1) * 32);
#pragma unroll
      for (int nj = 0; nj < 4; nj++)
        bN[nj] = *(const bf16x8*)(Br + (size_t)nj * 16 * KVTSTR + (it + 1) * 32);
    }
#pragma unroll
    for (int i = 0; i < 8; i++) ks += (float)aC[i];
#pragma unroll
    for (int nj = 0; nj < 4; nj++)
      acc[nj] = __builtin_amdgcn_mfma_f32_16x16x32_bf16(aC, bC[nj], acc[nj], 0, 0, 0);
    aC = aN;
#pragma unroll
    for (int nj = 0; nj < 4; nj++) bC[nj] = bN[nj];
  }

  ks += __shfl_xor(ks, 16);
  ks += __shfl_xor(ks, 32);

  float* p = partial + (size_t)(kc * 64 + bh) * 4160;
#pragma unroll
  for (int nj = 0; nj < 4; nj++) {
    const int m = nj * 16 + (l & 15);
#pragma unroll
    for (int r = 0; r < 4; r++) {
      const int d = w * 16 + (l >> 4) * 4 + r;
      p[d * 64 + m] = acc[nj][r];
    }
  }
  if (l < 16) p[4096 + w * 16 + l] = ks;
}

// ---------------- finalize: 4 partials -> kvb[bh][80][64] bf16 ----------------
__global__ void kv_finalize(const float* __restrict__ partial, bf16* __restrict__ kvb) {
  const int bh = blockIdx.x;
  for (int i = threadIdx.x; i < 80 * 64; i += 256) {
    const int row = i >> 6;
    const int dd = i & 63;
    float outv = 0.f;
    if (row < 64) {
      float s = 0.f;
#pragma unroll
      for (int kc = 0; kc < 4; kc++)
        s += partial[(size_t)(kc * 64 + bh) * 4160 + dd * 64 + row];
      outv = s;
    } else if (row < 66) {
      float s = 0.f;
#pragma unroll
      for (int kc = 0; kc < 4; kc++)
        s += partial[(size_t)(kc * 64 + bh) * 4160 + 4096 + dd];
      bf16 hi = (bf16)s;
      outv = (row == 64) ? (float)hi : (s - (float)hi);
    }
    kvb[(size_t)bh * 5120 + row * 64 + dd] = (bf16)outv;
  }
}

// ---------------- attn out via MFMA ----------------
__global__ __launch_bounds__(256) void attn_mfma(const bf16* __restrict__ qbuf,
                                                 const bf16* __restrict__ kvb,
                                                 bf16* __restrict__ attn) {
  const int bh = blockIdx.x >> 4;
  const int tch = blockIdx.x & 15;
  const int b = bh >> 4;
  const int h = bh & 15;
  const int lane = threadIdx.x & 63;
  const int wave = threadIdx.x >> 6;
  const int t0 = tch * 256 + wave * 64;

  const bf16* kvp = kvb + (size_t)bh * 5120;
  bf16x8 bfrag[5][2];
#pragma unroll
  for (int j = 0; j < 5; j++)
#pragma unroll
    for (int kk = 0; kk < 2; kk++)
      bfrag[j][kk] = *(const bf16x8*)(kvp + (j * 16 + (lane & 15)) * 64 + kk * 32 + (lane >> 4) * 8);

  f32x4 acc[4][5] = {};
#pragma unroll
  for (int i = 0; i < 4; i++) {
    const int t = t0 + i * 16 + (lane & 15);
    const bf16* qp = qbuf + (size_t)(b * T_ + t) * 1024 + h * 64 + (lane >> 4) * 8;
    bf16x8 a0 = *(const bf16x8*)qp;
    bf16x8 a1 = *(const bf16x8*)(qp + 32);
#pragma unroll
    for (int j = 0; j < 5; j++) {
      acc[i][j] = __builtin_amdgcn_mfma_f32_16x16x32_bf16(a0, bfrag[j][0], acc[i][j], 0, 0, 0);
      acc[i][j] = __builtin_amdgcn_mfma_f32_16x16x32_bf16(a1, bfrag[j][1], acc[i][j], 0, 0, 0);
    }
  }

#pragma unroll
  for (int i = 0; i < 4; i++) {
#pragma unroll
    for (int r = 0; r < 4; r++) {
      float hi = __shfl(acc[i][4][r], (lane & 48));
      float lo = __shfl(acc[i][4][r], (lane & 48) + 1);
      float inv = 1.0f / (hi + lo + EPS_);
      const int t = t0 + i * 16 + (lane >> 4) * 4 + r;
      bf16* op = attn + (size_t)(b * T_ + t) * 1024 + h * 64 + (lane & 15);
#pragma unroll
      for (int j = 0; j < 4; j++)
        op[j * 16] = (bf16)(acc[i][j][r] * inv);
    }
  }
}

// ---------------- launch ----------------
extern "C" void kernel_launch(void* const* d_in, const int* in_sizes, int n_in,
                              void* d_out, int out_size, void* d_ws, size_t ws_size,
                              hipStream_t stream) {
  const float* x = (const float*)d_in[0];
  const float* Wqkv = (const float*)d_in[1];
  const float* Wproj = (const float*)d_in[2];
  const float* bproj = (const float*)d_in[3];
  float* out = (float*)d_out;

  char* w = (char*)d_ws;
  bf16* xw = (bf16*)w;      w += (size_t)16777216 * 2;
  bf16* wqkv = (bf16*)w;    w += (size_t)3145728 * 2;
  bf16* wproj = (bf16*)w;   w += (size_t)1048576 * 2;
  bf16* qbuf = (bf16*)w;    w += (size_t)16384 * 1024 * 2;
  bf16* kvt = (bf16*)w;     w += (size_t)2048 * KVTSTR * 2;
  bf16* attnb = (bf16*)w;   w += (size_t)16384 * 1024 * 2;
  float* partial = (float*)w; w += (size_t)4 * 64 * 4160 * 4;
  bf16* kvb = (bf16*)w;

  (void)hipFuncSetAttribute((const void*)gemm9<0>,
      hipFuncAttributeMaxDynamicSharedMemorySize, SMEMB);
  (void)hipFuncSetAttribute((const void*)gemm9<1>,
      hipFuncAttributeMaxDynamicSharedMemorySize, SMEMB);

  cast_kernel<<<8192, 256, 0, stream>>>(x, xw, 16777216 / 8);
  cast_kernel<<<1536, 256, 0, stream>>>(Wqkv, wqkv, 3145728 / 8);
  cast_kernel<<<512, 256, 0, stream>>>(Wproj, wproj, 1048576 / 8);

  // qkv = x @ Wqkv^T; q->qbuf (phi), k/v->kvt transposed (phi on k). grid 64x12=768
  gemm9<0><<<768, 512, SMEMB, stream>>>(xw, wqkv, (void*)qbuf, nullptr, kvt, 16384, 3072, 12);

  kvgemm<<<256, 256, 0, stream>>>(kvt, partial);
  kv_finalize<<<64, 256, 0, stream>>>(partial, kvb);

  attn_mfma<<<64 * 16, 256, 0, stream>>>(qbuf, kvb, attnb);

  // out = attn @ Wproj^T + bproj. grid 64x4=256
  gemm9<1><<<256, 512, SMEMB, stream>>>(attnb, wproj, (void*)out, bproj, nullptr, 16384, 1024, 4);
}

// Round 10
// 221.089 us; speedup vs baseline: 1.0327x; 1.0327x over previous
//
#include <hip/hip_runtime.h>

typedef __bf16 bf16;
typedef bf16 bf16x8 __attribute__((ext_vector_type(8)));
typedef bf16 bf16x4 __attribute__((ext_vector_type(4)));
typedef float f32x4 __attribute__((ext_vector_type(4)));

#define B_ 4
#define T_ 4096
#define C_ 1024
#define EPS_ 1e-6f
#define KVTSTR 16448  // 16384 + 64 pad

typedef __attribute__((address_space(1))) const void* as1p;
typedef __attribute__((address_space(3))) void* as3p;

// ---------------- fused cast f32 -> bf16 (x, Wqkv, Wproj in one launch) ----------------
__global__ void cast_all(const float* __restrict__ x, const float* __restrict__ wq,
                         const float* __restrict__ wp, bf16* __restrict__ xw,
                         bf16* __restrict__ wqw, bf16* __restrict__ wpw) {
  const int N0 = 16777216 / 8, N1 = 3145728 / 8, N2 = 1048576 / 8;
  int i = blockIdx.x * blockDim.x + threadIdx.x;
  const int stride = gridDim.x * blockDim.x;
  for (; i < N0 + N1 + N2; i += stride) {
    const float* src;
    bf16* dst;
    int j;
    if (i < N0) { src = x; dst = xw; j = i; }
    else if (i < N0 + N1) { src = wq; dst = wqw; j = i - N0; }
    else { src = wp; dst = wpw; j = i - N0 - N1; }
    const float4* p = (const float4*)(src + (size_t)j * 8);
    float4 v0 = p[0];
    float4 v1 = p[1];
    bf16x8 o;
    o[0] = (bf16)v0.x; o[1] = (bf16)v0.y; o[2] = (bf16)v0.z; o[3] = (bf16)v0.w;
    o[4] = (bf16)v1.x; o[5] = (bf16)v1.y; o[6] = (bf16)v1.z; o[7] = (bf16)v1.w;
    *(bf16x8*)(dst + (size_t)j * 8) = o;
  }
}

// ---------------- 4-phase NT GEMM with counted vmcnt (T4): C = A[M][K] * B[N][K]^T ------
// BM=BN=256, BK=64, 512 thr (8 waves, 2M x 4N, wave tile 128x64), double-buffered 128KB.
// Per K-tile: 4 phases {ds_read; [stage]; bar; lgkm0; 16 MFMA; [gate]; bar}.
// Stages: ph0 = B0..B3(t+1), ph1 = A0,A2,A1,A3(t+1).
// Gates (counted, never 0 in steady state):
//   end-ph1: vmcnt(8)  [in-flight 10 -> drains A1,A3(t) before ph2 reads them]
//   end-ph3: vmcnt(2)  [drains B0-3,A0,A2(t+1); leaves A1,A3(t+1) = entry invariant]
#define BM 256
#define BN 256
#define BK 64
#define KD 1024
#define NTI (KD / BK)                  // 16
#define TILB 32768                     // one operand tile: 256*64*2B
#define BUFB (2 * TILB)                // A + B = 65536
#define SMEMB (2 * BUFB)               // 131072

#define STG(p, ko, dst) __builtin_amdgcn_global_load_lds((as1p)((p) + (ko)), (as3p)(dst), 16, 0, 0)

#define LDA(MI0)                                                                       \
  _Pragma("unroll") for (int a = 0; a < 2; a++)                                        \
    _Pragma("unroll") for (int kk = 0; kk < 2; kk++)                                   \
      af[a][kk] = *(const bf16x8*)(Ab + (wm * 128 + ((MI0) + a) * 16 + fr) * 64 + swz[kk]);

#define MM(MI0)                                                                        \
  __builtin_amdgcn_s_setprio(1);                                                       \
  _Pragma("unroll") for (int a = 0; a < 2; a++)                                        \
    _Pragma("unroll") for (int nj = 0; nj < 4; nj++)                                   \
      _Pragma("unroll") for (int kk = 0; kk < 2; kk++)                                 \
        acc[(MI0) + a][nj] = __builtin_amdgcn_mfma_f32_16x16x32_bf16(af[a][kk], bfr[nj][kk], acc[(MI0) + a][nj], 0, 0, 0); \
  __builtin_amdgcn_s_setprio(0);

#define BAR1 { __builtin_amdgcn_s_barrier(); asm volatile("s_waitcnt lgkmcnt(0)" ::: "memory"); __builtin_amdgcn_sched_barrier(0); }
#define BAR2 { __builtin_amdgcn_s_barrier(); __builtin_amdgcn_sched_barrier(0); }

template <int MODE>
__global__ __launch_bounds__(512, 1) void gemmX(
    const bf16* __restrict__ A, const bf16* __restrict__ Bm,
    void* __restrict__ Cout, const float* __restrict__ bias,
    bf16* __restrict__ kvt, int M, int N, int tiles_n) {
  extern __shared__ char smem[];
  const int tid = threadIdx.x;
  const int l = tid & 63;
  const int w = tid >> 6;
  const int wm = w >> 2;   // 0..1  (M: 2 x 128)
  const int wn = w & 3;    // 0..3  (N: 4 x 64)

  const int cpx = gridDim.x >> 3;
  const int bid = (blockIdx.x & 7) * cpx + (blockIdx.x >> 3);
  const int tm = (bid / tiles_n) * BM;
  const int tn = (bid % tiles_n) * BN;

  // staging: thread covers row tid>>3 of a 64-row group, chunk tid&7 (16B);
  // LDS dest linear (tid*16); source chunk = (tid&7) ^ (row&7).
  const int gsw = ((tid & 7) ^ ((tid >> 3) & 7)) * 8;
  const int tsr = tid >> 3;

  const bf16* pA0 = A + (size_t)(tm + tsr) * KD + gsw;
  const bf16* pA1 = A + (size_t)(tm + 64 + tsr) * KD + gsw;
  const bf16* pA2 = A + (size_t)(tm + 128 + tsr) * KD + gsw;
  const bf16* pA3 = A + (size_t)(tm + 192 + tsr) * KD + gsw;
  const bf16* pB0 = Bm + (size_t)(tn + tsr) * KD + gsw;
  const bf16* pB1 = Bm + (size_t)(tn + 64 + tsr) * KD + gsw;
  const bf16* pB2 = Bm + (size_t)(tn + 128 + tsr) * KD + gsw;
  const bf16* pB3 = Bm + (size_t)(tn + 192 + tsr) * KD + gsw;

  // fragment read: row = base + fr; logical chunk c = kk*4+fc, physical = c ^ (row&7)
  const int fr = l & 15;
  const int fc = l >> 4;
  int swz[2];
  swz[0] = ((0 * 4 + fc) ^ (fr & 7)) * 8;
  swz[1] = ((1 * 4 + fc) ^ (fr & 7)) * 8;

  f32x4 acc[8][4] = {};

  // prologue: stage tile 0 into buf0, order B0-3, A0, A2, A1, A3; counted gate.
  STG(pB0, 0, smem + TILB + tid * 16);
  STG(pB1, 0, smem + TILB + 8192 + tid * 16);
  STG(pB2, 0, smem + TILB + 16384 + tid * 16);
  STG(pB3, 0, smem + TILB + 24576 + tid * 16);
  STG(pA0, 0, smem + tid * 16);
  STG(pA2, 0, smem + 16384 + tid * 16);
  STG(pA1, 0, smem + 8192 + tid * 16);
  STG(pA3, 0, smem + 24576 + tid * 16);
  asm volatile("s_waitcnt vmcnt(2)" ::: "memory");  // B0-3, A0, A2 landed; A1,A3 in flight
  __builtin_amdgcn_s_barrier();
  __builtin_amdgcn_sched_barrier(0);

  for (int t = 0; t < NTI; ++t) {
    const bf16* Ab = (const bf16*)(smem + (t & 1) * BUFB);
    const bf16* Bb = (const bf16*)(smem + (t & 1) * BUFB + TILB);
    char* sd = smem + ((t & 1) ^ 1) * BUFB;
    const bool st = (t + 1 < NTI);
    const int ko = (t + 1) * BK;
    bf16x8 bfr[4][2], af[2][2];

    // ---- phase 0: all B frags + A mi0,1 (rows in A0/A2); stage B of tile t+1 ----
#pragma unroll
    for (int nj = 0; nj < 4; nj++)
#pragma unroll
      for (int kk = 0; kk < 2; kk++)
        bfr[nj][kk] = *(const bf16x8*)(Bb + (wn * 64 + nj * 16 + fr) * 64 + swz[kk]);
    LDA(0)
    if (st) {
      STG(pB0, ko, sd + TILB + tid * 16);
      STG(pB1, ko, sd + TILB + 8192 + tid * 16);
      STG(pB2, ko, sd + TILB + 16384 + tid * 16);
      STG(pB3, ko, sd + TILB + 24576 + tid * 16);
    }
    BAR1 MM(0) BAR2

    // ---- phase 1: A mi2,3 (A0/A2); stage A of t+1 in order A0,A2,A1,A3; gate ----
    LDA(2)
    if (st) {
      STG(pA0, ko, sd + tid * 16);
      STG(pA2, ko, sd + 16384 + tid * 16);
      STG(pA1, ko, sd + 8192 + tid * 16);
      STG(pA3, ko, sd + 24576 + tid * 16);
    }
    BAR1 MM(2)
    if (st) { asm volatile("s_waitcnt vmcnt(8)" ::: "memory"); }  // drains A1,A3(t)
    else    { asm volatile("s_waitcnt vmcnt(0)" ::: "memory"); }
    BAR2

    // ---- phase 2: A mi4,5 (rows in A1/A3) ----
    LDA(4)
    BAR1 MM(4) BAR2

    // ---- phase 3: A mi6,7 (A1/A3); end-of-tile counted gate ----
    LDA(6)
    BAR1 MM(6)
    if (st) { asm volatile("s_waitcnt vmcnt(2)" ::: "memory"); }  // B,A0,A2(t+1) landed
    BAR2
  }

  // ---------------- epilogue: C/D col = lane&15, row = (lane>>4)*4 + r ----------------
  const int crow0 = tm + wm * 128 + (l >> 4) * 4;
  const int ccol0 = tn + wn * 64 + (l & 15);
  if (MODE == 0) {
    if (tn < 1024) {
      bf16* qbuf = (bf16*)Cout;
#pragma unroll
      for (int mi = 0; mi < 8; mi++)
#pragma unroll
        for (int nj = 0; nj < 4; nj++) {
          const int col = ccol0 + nj * 16;
#pragma unroll
          for (int r = 0; r < 4; r++) {
            const int row = crow0 + mi * 16 + r;
            float v = acc[mi][nj][r];
            v = (v > 0.f) ? (v + 1.0f) : __expf(v);
            qbuf[(size_t)row * 1024 + col] = (bf16)v;
          }
        }
    } else {
#pragma unroll
      for (int mi = 0; mi < 8; mi++)
#pragma unroll
        for (int nj = 0; nj < 4; nj++) {
          const int colp = ccol0 + nj * 16 - 1024;
          const bool isk = (colp < 1024);
          bf16x4 pk;
#pragma unroll
          for (int r = 0; r < 4; r++) {
            float v = acc[mi][nj][r];
            if (isk) v = (v > 0.f) ? (v + 1.0f) : __expf(v);
            pk[r] = (bf16)v;
          }
          const int n0 = crow0 + mi * 16;
          *(bf16x4*)(kvt + (size_t)colp * KVTSTR + n0) = pk;
        }
    }
  } else {
    float* Cf = (float*)Cout;
#pragma unroll
    for (int mi = 0; mi < 8; mi++)
#pragma unroll
      for (int nj = 0; nj < 4; nj++) {
        const int col = ccol0 + nj * 16;
        const float bv = bias[col];
#pragma unroll
        for (int r = 0; r < 4; r++) {
          const int row = crow0 + mi * 16 + r;
          Cf[(size_t)row * N + col] = acc[mi][nj][r] + bv;
        }
      }
  }
}

// ---------------- kvgemm: partial kv[d][m] (+ksum) per (kchunk, b, h) via MFMA ----------
__global__ __launch_bounds__(256) void kvgemm(const bf16* __restrict__ kvt,
                                              float* __restrict__ partial) {
  const int kc = blockIdx.x >> 6;
  const int bh = blockIdx.x & 63;
  const int b = bh >> 4, h = bh & 15;
  const int l = threadIdx.x & 63;
  const int w = threadIdx.x >> 6;

  const size_t nb = (size_t)b * 4096 + kc * 1024 + (l >> 4) * 8;
  const bf16* Ar = kvt + (size_t)(h * 64 + w * 16 + (l & 15)) * KVTSTR + nb;
  const bf16* Br = kvt + (size_t)(1024 + h * 64 + (l & 15)) * KVTSTR + nb;

  f32x4 acc[4] = {};
  float ks = 0.f;
  bf16x8 aC, bC[4], aN, bN[4];
  aC = *(const bf16x8*)Ar;
#pragma unroll
  for (int nj = 0; nj < 4; nj++) bC[nj] = *(const bf16x8*)(Br + (size_t)nj * 16 * KVTSTR);

  for (int it = 0; it < 32; ++it) {
    if (it + 1 < 32) {
      aN = *(const bf16x8*)(Ar + (it + 1) * 32);
#pragma unroll
      for (int nj = 0; nj < 4; nj++)
        bN[nj] = *(const bf16x8*)(Br + (size_t)nj * 16 * KVTSTR + (it + 1) * 32);
    }
#pragma unroll
    for (int i = 0; i < 8; i++) ks += (float)aC[i];
#pragma unroll
    for (int nj = 0; nj < 4; nj++)
      acc[nj] = __builtin_amdgcn_mfma_f32_16x16x32_bf16(aC, bC[nj], acc[nj], 0, 0, 0);
    aC = aN;
#pragma unroll
    for (int nj = 0; nj < 4; nj++) bC[nj] = bN[nj];
  }

  ks += __shfl_xor(ks, 16);
  ks += __shfl_xor(ks, 32);

  float* p = partial + (size_t)(kc * 64 + bh) * 4160;
#pragma unroll
  for (int nj = 0; nj < 4; nj++) {
    const int m = nj * 16 + (l & 15);
#pragma unroll
    for (int r = 0; r < 4; r++) {
      const int d = w * 16 + (l >> 4) * 4 + r;
      p[d * 64 + m] = acc[nj][r];
    }
  }
  if (l < 16) p[4096 + w * 16 + l] = ks;
}

// ---------------- finalize: 4 partials -> kvb[bh][80][64] bf16 ----------------
__global__ void kv_finalize(const float* __restrict__ partial, bf16* __restrict__ kvb) {
  const int bh = blockIdx.x;
  for (int i = threadIdx.x; i < 80 * 64; i += 256) {
    const int row = i >> 6;
    const int dd = i & 63;
    float outv = 0.f;
    if (row < 64) {
      float s = 0.f;
#pragma unroll
      for (int kc = 0; kc < 4; kc++)
        s += partial[(size_t)(kc * 64 + bh) * 4160 + dd * 64 + row];
      outv = s;
    } else if (row < 66) {
      float s = 0.f;
#pragma unroll
      for (int kc = 0; kc < 4; kc++)
        s += partial[(size_t)(kc * 64 + bh) * 4160 + 4096 + dd];
      bf16 hi = (bf16)s;
      outv = (row == 64) ? (float)hi : (s - (float)hi);
    }
    kvb[(size_t)bh * 5120 + row * 64 + dd] = (bf16)outv;
  }
}

// ---------------- attn out via MFMA ----------------
__global__ __launch_bounds__(256) void attn_mfma(const bf16* __restrict__ qbuf,
                                                 const bf16* __restrict__ kvb,
                                                 bf16* __restrict__ attn) {
  const int bh = blockIdx.x >> 4;
  const int tch = blockIdx.x & 15;
  const int b = bh >> 4;
  const int h = bh & 15;
  const int lane = threadIdx.x & 63;
  const int wave = threadIdx.x >> 6;
  const int t0 = tch * 256 + wave * 64;

  const bf16* kvp = kvb + (size_t)bh * 5120;
  bf16x8 bfrag[5][2];
#pragma unroll
  for (int j = 0; j < 5; j++)
#pragma unroll
    for (int kk = 0; kk < 2; kk++)
      bfrag[j][kk] = *(const bf16x8*)(kvp + (j * 16 + (lane & 15)) * 64 + kk * 32 + (lane >> 4) * 8);

  f32x4 acc[4][5] = {};
#pragma unroll
  for (int i = 0; i < 4; i++) {
    const int t = t0 + i * 16 + (lane & 15);
    const bf16* qp = qbuf + (size_t)(b * T_ + t) * 1024 + h * 64 + (lane >> 4) * 8;
    bf16x8 a0 = *(const bf16x8*)qp;
    bf16x8 a1 = *(const bf16x8*)(qp + 32);
#pragma unroll
    for (int j = 0; j < 5; j++) {
      acc[i][j] = __builtin_amdgcn_mfma_f32_16x16x32_bf16(a0, bfrag[j][0], acc[i][j], 0, 0, 0);
      acc[i][j] = __builtin_amdgcn_mfma_f32_16x16x32_bf16(a1, bfrag[j][1], acc[i][j], 0, 0, 0);
    }
  }

#pragma unroll
  for (int i = 0; i < 4; i++) {
#pragma unroll
    for (int r = 0; r < 4; r++) {
      float hi = __shfl(acc[i][4][r], (lane & 48));
      float lo = __shfl(acc[i][4][r], (lane & 48) + 1);
      float inv = 1.0f / (hi + lo + EPS_);
      const int t = t0 + i * 16 + (lane >> 4) * 4 + r;
      bf16* op = attn + (size_t)(b * T_ + t) * 1024 + h * 64 + (lane & 15);
#pragma unroll
      for (int j = 0; j < 4; j++)
        op[j * 16] = (bf16)(acc[i][j][r] * inv);
    }
  }
}

// ---------------- launch ----------------
extern "C" void kernel_launch(void* const* d_in, const int* in_sizes, int n_in,
                              void* d_out, int out_size, void* d_ws, size_t ws_size,
                              hipStream_t stream) {
  const float* x = (const float*)d_in[0];
  const float* Wqkv = (const float*)d_in[1];
  const float* Wproj = (const float*)d_in[2];
  const float* bproj = (const float*)d_in[3];
  float* out = (float*)d_out;

  char* w = (char*)d_ws;
  bf16* xw = (bf16*)w;      w += (size_t)16777216 * 2;
  bf16* wqkv = (bf16*)w;    w += (size_t)3145728 * 2;
  bf16* wproj = (bf16*)w;   w += (size_t)1048576 * 2;
  bf16* qbuf = (bf16*)w;    w += (size_t)16384 * 1024 * 2;
  bf16* kvt = (bf16*)w;     w += (size_t)2048 * KVTSTR * 2;
  bf16* attnb = (bf16*)w;   w += (size_t)16384 * 1024 * 2;
  float* partial = (float*)w; w += (size_t)4 * 64 * 4160 * 4;
  bf16* kvb = (bf16*)w;

  (void)hipFuncSetAttribute((const void*)gemmX<0>,
      hipFuncAttributeMaxDynamicSharedMemorySize, SMEMB);
  (void)hipFuncSetAttribute((const void*)gemmX<1>,
      hipFuncAttributeMaxDynamicSharedMemorySize, SMEMB);

  cast_all<<<2048, 256, 0, stream>>>(x, Wqkv, Wproj, xw, wqkv, wproj);

  // qkv = x @ Wqkv^T; q->qbuf (phi), k/v->kvt transposed (phi on k). grid 64x12=768
  gemmX<0><<<768, 512, SMEMB, stream>>>(xw, wqkv, (void*)qbuf, nullptr, kvt, 16384, 3072, 12);

  kvgemm<<<256, 256, 0, stream>>>(kvt, partial);
  kv_finalize<<<64, 256, 0, stream>>>(partial, kvb);

  attn_mfma<<<64 * 16, 256, 0, stream>>>(qbuf, kvb, attnb);

  // out = attn @ Wproj^T + bproj. grid 64x4=256
  gemmX<1><<<256, 512, SMEMB, stream>>>(attnb, wproj, (void*)out, bproj, nullptr, 16384, 1024, 4);
}

// Round 11
// 216.052 us; speedup vs baseline: 1.0568x; 1.0233x over previous
//
#include <hip/hip_runtime.h>

typedef __bf16 bf16;
typedef bf16 bf16x8 __attribute__((ext_vector_type(8)));
typedef bf16 bf16x4 __attribute__((ext_vector_type(4)));
typedef float f32x4 __attribute__((ext_vector_type(4)));

#define B_ 4
#define T_ 4096
#define C_ 1024
#define EPS_ 1e-6f
#define KVTSTR 16448  // 16384 + 64 pad

typedef __attribute__((address_space(1))) const void* as1p;
typedef __attribute__((address_space(3))) void* as3p;

// ---------------- fused cast f32 -> bf16 (x, Wqkv, Wproj in one launch) ----------------
__global__ void cast_all(const float* __restrict__ x, const float* __restrict__ wq,
                         const float* __restrict__ wp, bf16* __restrict__ xw,
                         bf16* __restrict__ wqw, bf16* __restrict__ wpw) {
  const int N0 = 16777216 / 8, N1 = 3145728 / 8, N2 = 1048576 / 8;
  int i = blockIdx.x * blockDim.x + threadIdx.x;
  const int stride = gridDim.x * blockDim.x;
  for (; i < N0 + N1 + N2; i += stride) {
    const float* src;
    bf16* dst;
    int j;
    if (i < N0) { src = x; dst = xw; j = i; }
    else if (i < N0 + N1) { src = wq; dst = wqw; j = i - N0; }
    else { src = wp; dst = wpw; j = i - N0 - N1; }
    const float4* p = (const float4*)(src + (size_t)j * 8);
    float4 v0 = p[0];
    float4 v1 = p[1];
    bf16x8 o;
    o[0] = (bf16)v0.x; o[1] = (bf16)v0.y; o[2] = (bf16)v0.z; o[3] = (bf16)v0.w;
    o[4] = (bf16)v1.x; o[5] = (bf16)v1.y; o[6] = (bf16)v1.z; o[7] = (bf16)v1.w;
    *(bf16x8*)(dst + (size_t)j * 8) = o;
  }
}

// ---------------- 4-phase NT GEMM, counted vmcnt, static unroll-2: C = A*B^T ----------
// BM=BN=256, BK=64, 512 thr (8 waves, 2M x 4N, wave tile 128x64), dbuf 128KB LDS.
// Per K-tile: 4 phases {ds_read; [stage]; bar; lgkm0; 16 MFMA; [gate]; bar}.
// Stages: ph0 = B0..B3(t+1), ph1 = A0,A2,A1,A3(t+1).
// Gates: end-ph1 vmcnt(8) [drains A1,A3(t)]; end-ph3 vmcnt(2) [leaves A1,A3(t+1)].
// K-loop unrolled in tile-pairs -> all LDS addresses compile-time constant.
#define BM 256
#define BN 256
#define BK 64
#define KD 1024
#define NTI (KD / BK)                  // 16
#define TILB 32768                     // one operand tile: 256*64*2B
#define BUFB (2 * TILB)                // A + B = 65536
#define SMEMB (2 * BUFB)               // 131072

#define STG(p, ko, dst) __builtin_amdgcn_global_load_lds((as1p)((p) + (ko)), (as3p)(dst), 16, 0, 0)

#define LDA(MI0)                                                                       \
  _Pragma("unroll") for (int a = 0; a < 2; a++)                                        \
    _Pragma("unroll") for (int kk = 0; kk < 2; kk++)                                   \
      af[a][kk] = *(const bf16x8*)(Ab + (wm * 128 + ((MI0) + a) * 16 + fr) * 64 + swz[kk]);

#define MM(MI0)                                                                        \
  __builtin_amdgcn_s_setprio(1);                                                       \
  _Pragma("unroll") for (int a = 0; a < 2; a++)                                        \
    _Pragma("unroll") for (int nj = 0; nj < 4; nj++)                                   \
      _Pragma("unroll") for (int kk = 0; kk < 2; kk++)                                 \
        acc[(MI0) + a][nj] = __builtin_amdgcn_mfma_f32_16x16x32_bf16(af[a][kk], bfr[nj][kk], acc[(MI0) + a][nj], 0, 0, 0); \
  __builtin_amdgcn_s_setprio(0);

#define BAR1 { __builtin_amdgcn_s_barrier(); asm volatile("s_waitcnt lgkmcnt(0)" ::: "memory"); __builtin_amdgcn_sched_barrier(0); }
#define BAR2 { __builtin_amdgcn_s_barrier(); __builtin_amdgcn_sched_barrier(0); }

// One K-tile. AB/BB: read bases (static). SD: stage dest buffer (static).
// ST: literal 0/1. KO: element offset of tile t+1.
#define KTILE(ABp, BBp, SDp, ST, KO)                                                   \
  {                                                                                    \
    const bf16* Ab = (const bf16*)(ABp);                                               \
    const bf16* Bb = (const bf16*)(BBp);                                               \
    char* sd = (char*)(SDp);                                                           \
    bf16x8 bfr[4][2], af[2][2];                                                        \
    /* phase 0: B frags + A mi0,1; stage B(t+1) */                                     \
    _Pragma("unroll") for (int nj = 0; nj < 4; nj++)                                   \
      _Pragma("unroll") for (int kk = 0; kk < 2; kk++)                                 \
        bfr[nj][kk] = *(const bf16x8*)(Bb + (wn * 64 + nj * 16 + fr) * 64 + swz[kk]);  \
    LDA(0)                                                                             \
    if (ST) {                                                                          \
      STG(pB0, KO, sd + TILB + tid * 16);                                              \
      STG(pB1, KO, sd + TILB + 8192 + tid * 16);                                       \
      STG(pB2, KO, sd + TILB + 16384 + tid * 16);                                      \
      STG(pB3, KO, sd + TILB + 24576 + tid * 16);                                      \
    }                                                                                  \
    BAR1 MM(0) BAR2                                                                    \
    /* phase 1: A mi2,3; stage A(t+1) order A0,A2,A1,A3; gate */                       \
    LDA(2)                                                                             \
    if (ST) {                                                                          \
      STG(pA0, KO, sd + tid * 16);                                                     \
      STG(pA2, KO, sd + 16384 + tid * 16);                                             \
      STG(pA1, KO, sd + 8192 + tid * 16);                                              \
      STG(pA3, KO, sd + 24576 + tid * 16);                                             \
    }                                                                                  \
    BAR1 MM(2)                                                                         \
    if (ST) { asm volatile("s_waitcnt vmcnt(8)" ::: "memory"); }                       \
    else    { asm volatile("s_waitcnt vmcnt(0)" ::: "memory"); }                       \
    BAR2                                                                               \
    /* phase 2: A mi4,5 */                                                             \
    LDA(4)                                                                             \
    BAR1 MM(4) BAR2                                                                    \
    /* phase 3: A mi6,7; counted end-of-tile gate */                                   \
    LDA(6)                                                                             \
    BAR1 MM(6)                                                                         \
    if (ST) { asm volatile("s_waitcnt vmcnt(2)" ::: "memory"); }                       \
    BAR2                                                                               \
  }

template <int MODE>
__global__ __launch_bounds__(512, 1) void gemmX(
    const bf16* __restrict__ A, const bf16* __restrict__ Bm,
    void* __restrict__ Cout, const float* __restrict__ bias,
    bf16* __restrict__ kvt, int M, int N, int tiles_n) {
  extern __shared__ char smem[];
  const int tid = threadIdx.x;
  const int l = tid & 63;
  const int w = tid >> 6;
  const int wm = w >> 2;   // 0..1  (M: 2 x 128)
  const int wn = w & 3;    // 0..3  (N: 4 x 64)

  const int cpx = gridDim.x >> 3;
  const int bid = (blockIdx.x & 7) * cpx + (blockIdx.x >> 3);
  const int tm = (bid / tiles_n) * BM;
  const int tn = (bid % tiles_n) * BN;

  // staging: thread covers row tid>>3 of a 64-row group, chunk tid&7 (16B);
  // LDS dest linear (tid*16); source chunk = (tid&7) ^ (row&7).
  const int gsw = ((tid & 7) ^ ((tid >> 3) & 7)) * 8;
  const int tsr = tid >> 3;

  const bf16* pA0 = A + (size_t)(tm + tsr) * KD + gsw;
  const bf16* pA1 = A + (size_t)(tm + 64 + tsr) * KD + gsw;
  const bf16* pA2 = A + (size_t)(tm + 128 + tsr) * KD + gsw;
  const bf16* pA3 = A + (size_t)(tm + 192 + tsr) * KD + gsw;
  const bf16* pB0 = Bm + (size_t)(tn + tsr) * KD + gsw;
  const bf16* pB1 = Bm + (size_t)(tn + 64 + tsr) * KD + gsw;
  const bf16* pB2 = Bm + (size_t)(tn + 128 + tsr) * KD + gsw;
  const bf16* pB3 = Bm + (size_t)(tn + 192 + tsr) * KD + gsw;

  // fragment read: row = base + fr; logical chunk c = kk*4+fc, physical = c ^ (row&7)
  const int fr = l & 15;
  const int fc = l >> 4;
  int swz[2];
  swz[0] = ((0 * 4 + fc) ^ (fr & 7)) * 8;
  swz[1] = ((1 * 4 + fc) ^ (fr & 7)) * 8;

  f32x4 acc[8][4] = {};

  // prologue: stage tile 0 into buf0, order B0-3, A0, A2, A1, A3; counted gate.
  STG(pB0, 0, smem + TILB + tid * 16);
  STG(pB1, 0, smem + TILB + 8192 + tid * 16);
  STG(pB2, 0, smem + TILB + 16384 + tid * 16);
  STG(pB3, 0, smem + TILB + 24576 + tid * 16);
  STG(pA0, 0, smem + tid * 16);
  STG(pA2, 0, smem + 16384 + tid * 16);
  STG(pA1, 0, smem + 8192 + tid * 16);
  STG(pA3, 0, smem + 24576 + tid * 16);
  asm volatile("s_waitcnt vmcnt(2)" ::: "memory");  // B0-3, A0, A2 landed; A1,A3 in flight
  __builtin_amdgcn_s_barrier();
  __builtin_amdgcn_sched_barrier(0);

  // K-loop: tile-pairs with static buffer addresses. Tile t even -> buf0, odd -> buf1.
#pragma unroll
  for (int tt = 0; tt < NTI - 2; tt += 2) {
    KTILE(smem, smem + TILB, smem + BUFB, 1, (size_t)(tt + 1) * BK)
    KTILE(smem + BUFB, smem + BUFB + TILB, smem, 1, (size_t)(tt + 2) * BK)
  }
  KTILE(smem, smem + TILB, smem + BUFB, 1, (size_t)(NTI - 1) * BK)  // tile 14 stages 15
  KTILE(smem + BUFB, smem + BUFB + TILB, smem, 0, 0)                // tile 15, no stage

  // ---------------- epilogue: C/D col = lane&15, row = (lane>>4)*4 + r ----------------
  const int crow0 = tm + wm * 128 + (l >> 4) * 4;
  const int ccol0 = tn + wn * 64 + (l & 15);
  if (MODE == 0) {
    if (tn < 1024) {
      bf16* qbuf = (bf16*)Cout;
#pragma unroll
      for (int mi = 0; mi < 8; mi++)
#pragma unroll
        for (int nj = 0; nj < 4; nj++) {
          const int col = ccol0 + nj * 16;
#pragma unroll
          for (int r = 0; r < 4; r++) {
            const int row = crow0 + mi * 16 + r;
            float v = acc[mi][nj][r];
            v = (v > 0.f) ? (v + 1.0f) : __expf(v);
            qbuf[(size_t)row * 1024 + col] = (bf16)v;
          }
        }
    } else {
#pragma unroll
      for (int mi = 0; mi < 8; mi++)
#pragma unroll
        for (int nj = 0; nj < 4; nj++) {
          const int colp = ccol0 + nj * 16 - 1024;
          const bool isk = (colp < 1024);
          bf16x4 pk;
#pragma unroll
          for (int r = 0; r < 4; r++) {
            float v = acc[mi][nj][r];
            if (isk) v = (v > 0.f) ? (v + 1.0f) : __expf(v);
            pk[r] = (bf16)v;
          }
          const int n0 = crow0 + mi * 16;
          *(bf16x4*)(kvt + (size_t)colp * KVTSTR + n0) = pk;
        }
    }
  } else {
    float* Cf = (float*)Cout;
#pragma unroll
    for (int mi = 0; mi < 8; mi++)
#pragma unroll
      for (int nj = 0; nj < 4; nj++) {
        const int col = ccol0 + nj * 16;
        const float bv = bias[col];
#pragma unroll
        for (int r = 0; r < 4; r++) {
          const int row = crow0 + mi * 16 + r;
          Cf[(size_t)row * N + col] = acc[mi][nj][r] + bv;
        }
      }
  }
}

// ---------------- kvgemm: partial kv[d][m] (+ksum) per (kchunk, b, h) via MFMA ----------
__global__ __launch_bounds__(256) void kvgemm(const bf16* __restrict__ kvt,
                                              float* __restrict__ partial) {
  const int kc = blockIdx.x >> 6;
  const int bh = blockIdx.x & 63;
  const int b = bh >> 4, h = bh & 15;
  const int l = threadIdx.x & 63;
  const int w = threadIdx.x >> 6;

  const size_t nb = (size_t)b * 4096 + kc * 1024 + (l >> 4) * 8;
  const bf16* Ar = kvt + (size_t)(h * 64 + w * 16 + (l & 15)) * KVTSTR + nb;
  const bf16* Br = kvt + (size_t)(1024 + h * 64 + (l & 15)) * KVTSTR + nb;

  f32x4 acc[4] = {};
  float ks = 0.f;
  bf16x8 aC, bC[4], aN, bN[4];
  aC = *(const bf16x8*)Ar;
#pragma unroll
  for (int nj = 0; nj < 4; nj++) bC[nj] = *(const bf16x8*)(Br + (size_t)nj * 16 * KVTSTR);

  for (int it = 0; it < 32; ++it) {
    if (it + 1 < 32) {
      aN = *(const bf16x8*)(Ar + (it + 1) * 32);
#pragma unroll
      for (int nj = 0; nj < 4; nj++)
        bN[nj] = *(const bf16x8*)(Br + (size_t)nj * 16 * KVTSTR + (it + 1) * 32);
    }
#pragma unroll
    for (int i = 0; i < 8; i++) ks += (float)aC[i];
#pragma unroll
    for (int nj = 0; nj < 4; nj++)
      acc[nj] = __builtin_amdgcn_mfma_f32_16x16x32_bf16(aC, bC[nj], acc[nj], 0, 0, 0);
    aC = aN;
#pragma unroll
    for (int nj = 0; nj < 4; nj++) bC[nj] = bN[nj];
  }

  ks += __shfl_xor(ks, 16);
  ks += __shfl_xor(ks, 32);

  float* p = partial + (size_t)(kc * 64 + bh) * 4160;
#pragma unroll
  for (int nj = 0; nj < 4; nj++) {
    const int m = nj * 16 + (l & 15);
#pragma unroll
    for (int r = 0; r < 4; r++) {
      const int d = w * 16 + (l >> 4) * 4 + r;
      p[d * 64 + m] = acc[nj][r];
    }
  }
  if (l < 16) p[4096 + w * 16 + l] = ks;
}

// ---------------- finalize: 4 partials -> kvb[bh][80][64] bf16 ----------------
__global__ void kv_finalize(const float* __restrict__ partial, bf16* __restrict__ kvb) {
  const int bh = blockIdx.x;
  for (int i = threadIdx.x; i < 80 * 64; i += 256) {
    const int row = i >> 6;
    const int dd = i & 63;
    float outv = 0.f;
    if (row < 64) {
      float s = 0.f;
#pragma unroll
      for (int kc = 0; kc < 4; kc++)
        s += partial[(size_t)(kc * 64 + bh) * 4160 + dd * 64 + row];
      outv = s;
    } else if (row < 66) {
      float s = 0.f;
#pragma unroll
      for (int kc = 0; kc < 4; kc++)
        s += partial[(size_t)(kc * 64 + bh) * 4160 + 4096 + dd];
      bf16 hi = (bf16)s;
      outv = (row == 64) ? (float)hi : (s - (float)hi);
    }
    kvb[(size_t)bh * 5120 + row * 64 + dd] = (bf16)outv;
  }
}

// ---------------- attn out via MFMA ----------------
__global__ __launch_bounds__(256) void attn_mfma(const bf16* __restrict__ qbuf,
                                                 const bf16* __restrict__ kvb,
                                                 bf16* __restrict__ attn) {
  const int bh = blockIdx.x >> 4;
  const int tch = blockIdx.x & 15;
  const int b = bh >> 4;
  const int h = bh & 15;
  const int lane = threadIdx.x & 63;
  const int wave = threadIdx.x >> 6;
  const int t0 = tch * 256 + wave * 64;

  const bf16* kvp = kvb + (size_t)bh * 5120;
  bf16x8 bfrag[5][2];
#pragma unroll
  for (int j = 0; j < 5; j++)
#pragma unroll
    for (int kk = 0; kk < 2; kk++)
      bfrag[j][kk] = *(const bf16x8*)(kvp + (j * 16 + (lane & 15)) * 64 + kk * 32 + (lane >> 4) * 8);

  f32x4 acc[4][5] = {};
#pragma unroll
  for (int i = 0; i < 4; i++) {
    const int t = t0 + i * 16 + (lane & 15);
    const bf16* qp = qbuf + (size_t)(b * T_ + t) * 1024 + h * 64 + (lane >> 4) * 8;
    bf16x8 a0 = *(const bf16x8*)qp;
    bf16x8 a1 = *(const bf16x8*)(qp + 32);
#pragma unroll
    for (int j = 0; j < 5; j++) {
      acc[i][j] = __builtin_amdgcn_mfma_f32_16x16x32_bf16(a0, bfrag[j][0], acc[i][j], 0, 0, 0);
      acc[i][j] = __builtin_amdgcn_mfma_f32_16x16x32_bf16(a1, bfrag[j][1], acc[i][j], 0, 0, 0);
    }
  }

#pragma unroll
  for (int i = 0; i < 4; i++) {
#pragma unroll
    for (int r = 0; r < 4; r++) {
      float hi = __shfl(acc[i][4][r], (lane & 48));
      float lo = __shfl(acc[i][4][r], (lane & 48) + 1);
      float inv = 1.0f / (hi + lo + EPS_);
      const int t = t0 + i * 16 + (lane >> 4) * 4 + r;
      bf16* op = attn + (size_t)(b * T_ + t) * 1024 + h * 64 + (lane & 15);
#pragma unroll
      for (int j = 0; j < 4; j++)
        op[j * 16] = (bf16)(acc[i][j][r] * inv);
    }
  }
}

// ---------------- launch ----------------
extern "C" void kernel_launch(void* const* d_in, const int* in_sizes, int n_in,
                              void* d_out, int out_size, void* d_ws, size_t ws_size,
                              hipStream_t stream) {
  const float* x = (const float*)d_in[0];
  const float* Wqkv = (const float*)d_in[1];
  const float* Wproj = (const float*)d_in[2];
  const float* bproj = (const float*)d_in[3];
  float* out = (float*)d_out;

  char* w = (char*)d_ws;
  bf16* xw = (bf16*)w;      w += (size_t)16777216 * 2;
  bf16* wqkv = (bf16*)w;    w += (size_t)3145728 * 2;
  bf16* wproj = (bf16*)w;   w += (size_t)1048576 * 2;
  bf16* qbuf = (bf16*)w;    w += (size_t)16384 * 1024 * 2;
  bf16* kvt = (bf16*)w;     w += (size_t)2048 * KVTSTR * 2;
  bf16* attnb = (bf16*)w;   w += (size_t)16384 * 1024 * 2;
  float* partial = (float*)w; w += (size_t)4 * 64 * 4160 * 4;
  bf16* kvb = (bf16*)w;

  (void)hipFuncSetAttribute((const void*)gemmX<0>,
      hipFuncAttributeMaxDynamicSharedMemorySize, SMEMB);
  (void)hipFuncSetAttribute((const void*)gemmX<1>,
      hipFuncAttributeMaxDynamicSharedMemorySize, SMEMB);

  cast_all<<<2048, 256, 0, stream>>>(x, Wqkv, Wproj, xw, wqkv, wproj);

  // qkv = x @ Wqkv^T; q->qbuf (phi), k/v->kvt transposed (phi on k). grid 64x12=768
  gemmX<0><<<768, 512, SMEMB, stream>>>(xw, wqkv, (void*)qbuf, nullptr, kvt, 16384, 3072, 12);

  kvgemm<<<256, 256, 0, stream>>>(kvt, partial);
  kv_finalize<<<64, 256, 0, stream>>>(partial, kvb);

  attn_mfma<<<64 * 16, 256, 0, stream>>>(qbuf, kvb, attnb);

  // out = attn @ Wproj^T + bproj. grid 64x4=256
  gemmX<1><<<256, 512, SMEMB, stream>>>(attnb, wproj, (void*)out, bproj, nullptr, 16384, 1024, 4);
}